// Round 1
// baseline (3378.297 us; speedup 1.0000x reference)
//
#include <hip/hip_runtime.h>

#define NPTS   1000000
#define KSTEPS 32
#define NF     8
#define IMG_H  1024
#define IMG_W  1024
#define FID    1000

__global__ __launch_bounds__(256) void flame_kernel(
    const float* __restrict__ palette,
    const float* __restrict__ Amat,
    const float* __restrict__ bvec,
    const float* __restrict__ fcolor,
    const float* __restrict__ xy0,
    const float* __restrict__ c0,
    const float* __restrict__ minv,
    const float* __restrict__ rangev,
    const int*   __restrict__ fn_idx,
    const int*   __restrict__ skipk_ptr,
    float*       __restrict__ img)
{
    __shared__ __align__(16) float s_pal[FID * 4];
    __shared__ float s_A[NF * 4];
    __shared__ float s_b[NF * 2];
    __shared__ float s_fc[NF];

    // Stage palette (16 KB) vectorized, plus the tiny A/b/fcolor tables.
    for (int t = threadIdx.x; t < FID; t += 256)
        ((float4*)s_pal)[t] = ((const float4*)palette)[t];
    if (threadIdx.x < NF * 4) s_A[threadIdx.x] = Amat[threadIdx.x];
    if (threadIdx.x < NF * 2) s_b[threadIdx.x] = bvec[threadIdx.x];
    if (threadIdx.x < NF)     s_fc[threadIdx.x] = fcolor[threadIdx.x];
    __syncthreads();

    const int i = blockIdx.x * 256 + threadIdx.x;
    if (i >= NPTS) return;

    const int   skipk = skipk_ptr[0];
    const float minx = minv[0], miny = minv[1];
    const float rx   = rangev[0], ry = rangev[1];

    const float2 xyv = ((const float2*)xy0)[i];
    float x = xyv.x, y = xyv.y;
    float c = c0[i];

    for (int k = 0; k < KSTEPS; ++k) {
        const int idx = fn_idx[(size_t)k * NPTS + i];

        // xy = A[idx] @ xy + b[idx]   (numpy-style: no FMA contraction)
        const float a00 = s_A[idx * 4 + 0], a01 = s_A[idx * 4 + 1];
        const float a10 = s_A[idx * 4 + 2], a11 = s_A[idx * 4 + 3];
        const float b0  = s_b[idx * 2 + 0], b1  = s_b[idx * 2 + 1];
        const float nx = __fadd_rn(__fadd_rn(__fmul_rn(a00, x), __fmul_rn(a01, y)), b0);
        const float ny = __fadd_rn(__fadd_rn(__fmul_rn(a10, x), __fmul_rn(a11, y)), b1);
        x = nx; y = ny;

        // c = (c + fcolor[idx]) * 0.5
        c = __fmul_rn(__fadd_rn(c, s_fc[idx]), 0.5f);

        // bins = ((xy - min_vec) * range_vec).astype(int32)  (trunc toward 0)
        const int xb = (int)__fmul_rn(__fsub_rn(x, minx), rx);
        const int yb = (int)__fmul_rn(__fsub_rn(y, miny), ry);

        const bool inb = (xb >= 0) & (xb < IMG_W) & (yb >= 0) & (yb < IMG_H) & (k >= skipk);
        if (inb) {
            // pal_idx = int(c * (fid-1) + 0.5/fid), clipped
            int pi = (int)__fadd_rn(__fmul_rn(c, 999.0f), 0.0005f);
            pi = min(max(pi, 0), FID - 1);
            const float4 col = *(const float4*)&s_pal[pi * 4];

            const size_t base = (size_t)xb * IMG_W + yb;
            atomicAdd(&img[base + 0 * (size_t)IMG_H * IMG_W], col.x);
            atomicAdd(&img[base + 1 * (size_t)IMG_H * IMG_W], col.y);
            atomicAdd(&img[base + 2 * (size_t)IMG_H * IMG_W], col.z);
            atomicAdd(&img[base + 3 * (size_t)IMG_H * IMG_W], col.w);
        }
    }
}

extern "C" void kernel_launch(void* const* d_in, const int* in_sizes, int n_in,
                              void* d_out, int out_size, void* d_ws, size_t ws_size,
                              hipStream_t stream) {
    const float* raw_image = (const float*)d_in[0];
    const float* palette   = (const float*)d_in[1];
    const float* A         = (const float*)d_in[2];
    const float* b         = (const float*)d_in[3];
    const float* fcolor    = (const float*)d_in[4];
    const float* xy0       = (const float*)d_in[5];
    const float* c0        = (const float*)d_in[6];
    const float* minv      = (const float*)d_in[7];
    const float* rangev    = (const float*)d_in[8];
    const int*   fn_idx    = (const int*)d_in[9];
    const int*   skipk     = (const int*)d_in[10];
    float* img = (float*)d_out;

    // Initialize accumulator from raw_image (zeros in the reference setup).
    hipMemcpyAsync(img, raw_image, (size_t)out_size * sizeof(float),
                   hipMemcpyDeviceToDevice, stream);

    dim3 grid((NPTS + 255) / 256);
    flame_kernel<<<grid, 256, 0, stream>>>(palette, A, b, fcolor, xy0, c0,
                                           minv, rangev, fn_idx, skipk, img);
}